// Round 11
// baseline (356.256 us; speedup 1.0000x reference)
//
#include <hip/hip_runtime.h>
#include <hip/hip_bf16.h>

#define B_ 8
#define C_ 512
#define T_ 8
#define H_ 28
#define W_ 28
#define N_ (T_*H_*W_)   // 6272
#define HP_ 14
#define WP_ 14
#define M_ (T_*HP_*WP_) // 1568
#define DI_ 256
#define DO_ 512
#define BN_EPS 1e-5f
#define SCALE_LOG2E 0.090168440055560214f  // (1/sqrt(256)) * log2(e)
#define PSUM_COLS 392                       // 8 batch * 49 nchunk
#define PG_BS 425984                        // padded per-batch stride (shorts): 1664*256 == 52*8192
#define Q_SCALE 32768.0f
#define Q_INV   3.0517578125e-05f

typedef __attribute__((ext_vector_type(8))) short short8;
typedef __attribute__((ext_vector_type(4))) short short4v;
typedef __attribute__((ext_vector_type(4))) float float4v;
typedef __attribute__((ext_vector_type(16))) float float16v;
typedef __attribute__((ext_vector_type(2))) float float2v;

__device__ inline unsigned short f2bf(float f) {
    union { float f; unsigned int u; } v; v.f = f;
    unsigned int u = v.u;
    return (unsigned short)((u + 0x7FFFu + ((u >> 16) & 1u)) >> 16);
}
__device__ inline float bf2f(unsigned short h) {
    union { unsigned int u; float f; } v; v.u = ((unsigned int)h) << 16;
    return v.f;
}
// raw barrier: does NOT drain vmcnt (unlike __syncthreads)
__device__ inline void blockbar() {
    asm volatile("" ::: "memory");
    __builtin_amdgcn_s_barrier();
    asm volatile("" ::: "memory");
}

// ---------- transpose + cast x [C,N] f32 -> xT [N,C] bf16 (per b) ----------
__global__ void xpose_x(const float* __restrict__ x, unsigned short* __restrict__ xT) {
    __shared__ float tile[64][65];
    int b = blockIdx.z;
    int c0 = blockIdx.y * 64, n0 = blockIdx.x * 64;
    const float* src = x + (size_t)b * C_ * N_;
    int tx = threadIdx.x & 63, ty = threadIdx.x >> 6;
#pragma unroll
    for (int i = 0; i < 16; i++) {
        int c = ty + i * 4;
        tile[c][tx] = src[(size_t)(c0 + c) * N_ + n0 + tx];
    }
    __syncthreads();
    unsigned short* d = xT + ((size_t)b * N_ + n0) * C_ + c0;
#pragma unroll
    for (int i = 0; i < 16; i++) {
        int n = ty + i * 4;
        d[(size_t)n * C_ + tx] = f2bf(tile[tx][n]);
    }
}

// ---------- maxpool(1,2,2) from xT: mpT[b][p][c] = max of 4 xT rows ----------
// max is monotone: max of bf16-rounded == bf16-round of max -> bitwise identical to old path.
__global__ void pool_from_xT(const unsigned short* __restrict__ xT, unsigned short* __restrict__ mpT) {
    int b = blockIdx.y;
    int p = blockIdx.x;                     // 0..1567
    int t = p / 196, pp = p - t * 196;
    int hp = pp / 14, wp = pp - hp * 14;
    int n00 = t * 784 + (2 * hp) * 28 + 2 * wp;
    const unsigned short* r0 = xT + ((size_t)b * N_ + n00) * C_;
    int c = threadIdx.x * 2;
    unsigned int a = *(const unsigned int*)(r0 + c);
    unsigned int bb = *(const unsigned int*)(r0 + C_ + c);
    unsigned int cc = *(const unsigned int*)(r0 + 28 * C_ + c);
    unsigned int dd = *(const unsigned int*)(r0 + 29 * C_ + c);
    float lo = fmaxf(fmaxf(bf2f(a & 0xFFFF), bf2f(bb & 0xFFFF)),
                     fmaxf(bf2f(cc & 0xFFFF), bf2f(dd & 0xFFFF)));
    float hi = fmaxf(fmaxf(bf2f(a >> 16), bf2f(bb >> 16)),
                     fmaxf(bf2f(cc >> 16), bf2f(dd >> 16)));
    unsigned int r = (unsigned int)f2bf(lo) | ((unsigned int)f2bf(hi) << 16);
    *(unsigned int*)(mpT + ((size_t)b * M_ + p) * C_ + c) = r;
}

// ---------- cast all 4 weight arrays (each 131072 elems) ----------
__global__ void cast_w4(const float* __restrict__ a0, const float* __restrict__ a1,
                        const float* __restrict__ a2, const float* __restrict__ a3,
                        unsigned short* __restrict__ d0, unsigned short* __restrict__ d1,
                        unsigned short* __restrict__ d2, unsigned short* __restrict__ d3) {
    int i = blockIdx.x * 256 + threadIdx.x;
    const float* s; unsigned short* d;
    switch (blockIdx.y) {
        case 0: s = a0; d = d0; break;
        case 1: s = a1; d = d1; break;
        case 2: s = a2; d = d2; break;
        default: s = a3; d = d3; break;
    }
    d[i] = f2bf(s[i]);
}

// ---------- unified projection GEMM (theta/phi/g), LDS-staged, raw barriers ----------
template<int GL>
__global__ __launch_bounds__(256, 2) void proj_gemm(
        const unsigned short* __restrict__ A, int MR,
        const unsigned short* __restrict__ W,
        unsigned short* __restrict__ Dp, size_t dBatch,
        const float* __restrict__ bias) {
    __shared__ __align__(16) unsigned short wqs[2][32][512];   // 64KB
    __shared__ __align__(16) unsigned short gscr[GL ? 4096 : 4];
    const int bid = blockIdx.x;
    const int b = bid & 7;
    const int nblk = bid >> 3;
    const int wave = threadIdx.x >> 6, lane = threadIdx.x & 63;
    const int lr = lane & 15, lk = lane >> 4;
    const unsigned short* Ab = A + (size_t)b * MR * C_;
    const int rbase = nblk * 128 + wave * 32;

    short8 a[2][16];
#pragma unroll
    for (int i = 0; i < 2; i++) {
        int row = rbase + i * 16 + lr; if (row >= MR) row = MR - 1;
#pragma unroll
        for (int kd = 0; kd < 16; kd++)
            a[i][kd] = *(const short8*)(Ab + (size_t)row * C_ + kd * 32 + lk * 8);
    }

    auto stage = [&](int bufi, int t) {
#pragma unroll
        for (int j = 0; j < 8; j++) {
            int row = wave * 8 + j;
            int qq = (lane * 16) ^ ((row & 7) << 4);
            const unsigned short* src = W + (size_t)(t * 32 + row) * C_ + (qq >> 1);
            unsigned short* dst = &wqs[bufi][0][0] + row * 512;
            __builtin_amdgcn_global_load_lds(
                (const __attribute__((address_space(1))) unsigned int*)src,
                (__attribute__((address_space(3))) unsigned int*)dst, 16, 0, 0);
        }
    };

    stage(0, 0);
    const int hq = (lk * 16) ^ ((lr & 7) << 4);
    unsigned short* Dlin = Dp + (size_t)b * dBatch + (size_t)rbase * DI_;
    unsigned short* Dg = Dp + (size_t)b * dBatch;
    int buf = 0;
#pragma unroll
    for (int t = 0; t < 8; t++) {
        if (t < 7) {
            stage(buf ^ 1, t + 1);
            if (t == 0) { asm volatile("s_waitcnt vmcnt(8)" ::: "memory"); }
            else if (GL == 0) { asm volatile("s_waitcnt vmcnt(24)" ::: "memory"); }
            else { asm volatile("s_waitcnt vmcnt(10)" ::: "memory"); }
        } else {
            if (GL == 0) { asm volatile("s_waitcnt vmcnt(16)" ::: "memory"); }
            else { asm volatile("s_waitcnt vmcnt(2)" ::: "memory"); }
        }
        blockbar();
        const char* Wb = (const char*)&wqs[buf][0][0];
        float4v acc[2][2] = {};
#pragma unroll
        for (int kd = 0; kd < 16; kd++) {
            short8 b0 = *(const short8*)(Wb + lr * 1024 + ((kd * 64) ^ hq));
            short8 b1 = *(const short8*)(Wb + (16 + lr) * 1024 + ((kd * 64) ^ hq));
            acc[0][0] = __builtin_amdgcn_mfma_f32_16x16x32_bf16(a[0][kd], b0, acc[0][0], 0, 0, 0);
            acc[0][1] = __builtin_amdgcn_mfma_f32_16x16x32_bf16(a[0][kd], b1, acc[0][1], 0, 0, 0);
            acc[1][0] = __builtin_amdgcn_mfma_f32_16x16x32_bf16(a[1][kd], b0, acc[1][0], 0, 0, 0);
            acc[1][1] = __builtin_amdgcn_mfma_f32_16x16x32_bf16(a[1][kd], b1, acc[1][1], 0, 0, 0);
        }
        if (GL == 0) {
#pragma unroll
            for (int i = 0; i < 2; i++)
#pragma unroll
                for (int j = 0; j < 2; j++) {
                    int col = t * 32 + j * 16 + lr;
                    float bv = bias[col];
#pragma unroll
                    for (int r = 0; r < 4; r++) {
                        int row = i * 16 + lk * 4 + r;
                        Dlin[(size_t)row * DI_ + col] = f2bf(acc[i][j][r] + bv);
                    }
                }
        } else {
#pragma unroll
            for (int i = 0; i < 2; i++) {
                int sm = (i * 2 + (lk >> 1)) & 3;
#pragma unroll
                for (int j = 0; j < 2; j++) {
                    int dd = j * 16 + lr;
                    int slot = dd * 4 + (sm ^ ((dd >> 3) & 3));
                    float bv = bias[t * 32 + dd];
                    short4v pk;
#pragma unroll
                    for (int r = 0; r < 4; r++) pk[r] = (short)f2bf(acc[i][j][r] + bv);
                    *(short4v*)(&gscr[wave * 1024 + slot * 8 + (lk & 1) * 4]) = pk;
                }
            }
            asm volatile("s_waitcnt lgkmcnt(0)" ::: "memory");
            blockbar();
#pragma unroll
            for (int r2 = 0; r2 < 2; r2++) {
                int idx = r2 * 256 + threadIdx.x;
                int w = idx >> 7;
                int o2 = (idx * 8) & 1023;
                short8 v = *(const short8*)(&gscr[idx * 8]);
                *(short8*)(Dg + (size_t)(nblk * 4 + w) * 8192 + t * 1024 + o2) = v;
            }
        }
        blockbar();
        buf ^= 1;
    }
}

// ---------- out GEMM, LDS-staged, int16 fixed-point output + fused BN partial sums ----------
__global__ __launch_bounds__(256, 2) void out_gemm(
        const unsigned short* __restrict__ wo,
        const unsigned short* __restrict__ Bh, const unsigned short* __restrict__ Bl,
        unsigned short* __restrict__ Dp, const float* __restrict__ bias,
        float* __restrict__ psum) {
    __shared__ __align__(16) unsigned short tts[2][2][32][256];  // 64KB
    const int bid = blockIdx.x;
    const int b = bid & 7;
    const int rem = bid >> 3;
    const int doblk = rem & 3;
    const int nchunk = rem >> 2;
    const int wave = threadIdx.x >> 6, lane = threadIdx.x & 63;
    const int lr = lane & 15, lk = lane >> 4;
    const unsigned short* Ab = wo + (size_t)(doblk * 128 + wave * 32) * DI_;
    const unsigned short* BhB = Bh + ((size_t)b * N_ + nchunk * 128) * DI_;
    const unsigned short* BlB = Bl + ((size_t)b * N_ + nchunk * 128) * DI_;

    short8 a[2][8];
#pragma unroll
    for (int i = 0; i < 2; i++)
#pragma unroll
        for (int kd = 0; kd < 8; kd++)
            a[i][kd] = *(const short8*)(Ab + (size_t)(i * 16 + lr) * DI_ + kd * 32 + lk * 8);

    auto stage = [&](int bufi, int t) {
#pragma unroll
        for (int p = 0; p < 2; p++) {
            const unsigned short* S = p ? BlB : BhB;
#pragma unroll
            for (int j = 0; j < 4; j++) {
                int chunk = wave * 4 + j;
                int row = chunk * 2 + (lane >> 5);
                int qq = (((lane & 31) * 16)) ^ ((row & 7) << 4);
                const unsigned short* src = S + (size_t)(t * 32 + row) * DI_ + (qq >> 1);
                unsigned short* dst = &tts[bufi][p][0][0] + chunk * 512;
                __builtin_amdgcn_global_load_lds(
                    (const __attribute__((address_space(1))) unsigned int*)src,
                    (__attribute__((address_space(3))) unsigned int*)dst, 16, 0, 0);
            }
        }
    };

    stage(0, 0);
    const int hq = (lk * 16) ^ ((lr & 7) << 4);
    float4v acc[4][2][2] = {};
    int buf = 0;
#pragma unroll
    for (int t = 0; t < 4; t++) {
        if (t < 3) {
            stage(buf ^ 1, t + 1);
            asm volatile("s_waitcnt vmcnt(8)" ::: "memory");
        } else {
            asm volatile("s_waitcnt vmcnt(0)" ::: "memory");
        }
        blockbar();
        const char* th = (const char*)&tts[buf][0][0][0];
        const char* tl = (const char*)&tts[buf][1][0][0];
#pragma unroll
        for (int kd = 0; kd < 8; kd++) {
            short8 bh0 = *(const short8*)(th + lr * 512 + ((kd * 64) ^ hq));
            short8 bh1 = *(const short8*)(th + (16 + lr) * 512 + ((kd * 64) ^ hq));
            short8 bl0 = *(const short8*)(tl + lr * 512 + ((kd * 64) ^ hq));
            short8 bl1 = *(const short8*)(tl + (16 + lr) * 512 + ((kd * 64) ^ hq));
            acc[t][0][0] = __builtin_amdgcn_mfma_f32_16x16x32_bf16(a[0][kd], bh0, acc[t][0][0], 0, 0, 0);
            acc[t][0][0] = __builtin_amdgcn_mfma_f32_16x16x32_bf16(a[0][kd], bl0, acc[t][0][0], 0, 0, 0);
            acc[t][0][1] = __builtin_amdgcn_mfma_f32_16x16x32_bf16(a[0][kd], bh1, acc[t][0][1], 0, 0, 0);
            acc[t][0][1] = __builtin_amdgcn_mfma_f32_16x16x32_bf16(a[0][kd], bl1, acc[t][0][1], 0, 0, 0);
            acc[t][1][0] = __builtin_amdgcn_mfma_f32_16x16x32_bf16(a[1][kd], bh0, acc[t][1][0], 0, 0, 0);
            acc[t][1][0] = __builtin_amdgcn_mfma_f32_16x16x32_bf16(a[1][kd], bl0, acc[t][1][0], 0, 0, 0);
            acc[t][1][1] = __builtin_amdgcn_mfma_f32_16x16x32_bf16(a[1][kd], bh1, acc[t][1][1], 0, 0, 0);
            acc[t][1][1] = __builtin_amdgcn_mfma_f32_16x16x32_bf16(a[1][kd], bl1, acc[t][1][1], 0, 0, 0);
        }
        blockbar();
        buf ^= 1;
    }
    unsigned short* Db = Dp + (size_t)b * DO_ * N_;
    float s1[2][4] = {}, s2[2][4] = {};
#pragma unroll
    for (int t = 0; t < 4; t++)
#pragma unroll
        for (int i = 0; i < 2; i++)
#pragma unroll
            for (int r = 0; r < 4; r++) {
                int dorow = doblk * 128 + wave * 32 + i * 16 + lk * 4 + r;
                float bv = bias[dorow];
                float v0 = acc[t][i][0][r] + bv;
                float v1 = acc[t][i][1][r] + bv;
                int ncol = nchunk * 128 + t * 32 + lr;
                float c0 = fminf(fmaxf(v0 * Q_SCALE, -32767.f), 32767.f);
                float c1 = fminf(fmaxf(v1 * Q_SCALE, -32767.f), 32767.f);
                Db[(size_t)dorow * N_ + ncol] = (unsigned short)(short)lrintf(c0);
                Db[(size_t)dorow * N_ + ncol + 16] = (unsigned short)(short)lrintf(c1);
                s1[i][r] += v0 + v1;
                s2[i][r] += v0 * v0 + v1 * v1;
            }
#pragma unroll
    for (int m = 1; m < 16; m <<= 1)
#pragma unroll
        for (int i = 0; i < 2; i++)
#pragma unroll
            for (int r = 0; r < 4; r++) {
                s1[i][r] += __shfl_xor(s1[i][r], m, 64);
                s2[i][r] += __shfl_xor(s2[i][r], m, 64);
            }
    if (lr == 0) {
        int pcol = b * 49 + nchunk;
#pragma unroll
        for (int i = 0; i < 2; i++)
#pragma unroll
            for (int r = 0; r < 4; r++) {
                int row = doblk * 128 + wave * 32 + i * 16 + lk * 4 + r;
                psum[(size_t)row * PSUM_COLS + pcol] = s1[i][r];
                psum[(size_t)(DO_ + row) * PSUM_COLS + pcol] = s2[i][r];
            }
    }
}

// ---------- fused attention v5: 64 q-rows/wave (2 sets), 2-wave blocks ----------
// Each LDS fragment read now feeds 2 MFMAs (register blocking on the n axis).
__global__ __launch_bounds__(128, 1) void attn_k(
        const unsigned short* __restrict__ thetaT,
        const unsigned short* __restrict__ phiT,
        const unsigned short* __restrict__ g,
        unsigned short* __restrict__ ttH,
        unsigned short* __restrict__ ttL) {
    __shared__ __align__(16) unsigned short phi_s[2][32][256];  // 32KB
    __shared__ __align__(16) unsigned short g_s[2][8192];       // 32KB
    const int bid = blockIdx.x;
    const int b = bid & 7;
    const int nblk = bid >> 3;
    const int wave = threadIdx.x >> 6, lane = threadIdx.x & 63;  // wave in 0..1
    const int l31 = lane & 31, hi = lane >> 5;
    const int n0 = nblk * 128 + wave * 64;
    const unsigned short* Q  = thetaT + ((size_t)b * N_ + n0) * DI_;
    const unsigned short* Pg = phiT + (size_t)b * PG_BS;
    const unsigned short* G  = g + (size_t)b * PG_BS;

    short8 q0[16], q1[16];
#pragma unroll
    for (int kb = 0; kb < 16; kb++) {
        q0[kb] = *(const short8*)(Q + (size_t)l31 * DI_ + kb * 16 + hi * 8);
        q1[kb] = *(const short8*)(Q + (size_t)(32 + l31) * DI_ + kb * 16 + hi * 8);
    }

    float16v acc0[8] = {}, acc1[8] = {};
    float rs0 = 0.f, rs1 = 0.f;

    auto stage = [&](int bufi, int t) {
        const unsigned short* phiRow = Pg + (size_t)t * 32 * DI_;
#pragma unroll
        for (int j = 0; j < 8; j++) {
            int chunk = wave * 8 + j;
            int row = chunk * 2 + (lane >> 5);
            int qq = ((lane & 31) * 16) ^ ((row & 31) << 4);
            const unsigned short* src = phiRow + (size_t)row * DI_ + (qq >> 1);
            unsigned short* dst = &phi_s[bufi][0][0] + chunk * 512;
            __builtin_amdgcn_global_load_lds(
                (const __attribute__((address_space(1))) unsigned int*)src,
                (__attribute__((address_space(3))) unsigned int*)dst, 16, 0, 0);
        }
        const unsigned short* Gt = G + (size_t)t * 8192;
#pragma unroll
        for (int j = 0; j < 8; j++) {
            int chunk = wave * 8 + j;
            const unsigned short* src = Gt + chunk * 512 + lane * 8;
            unsigned short* dst = &g_s[bufi][0] + chunk * 512;
            __builtin_amdgcn_global_load_lds(
                (const __attribute__((address_space(1))) unsigned int*)src,
                (__attribute__((address_space(3))) unsigned int*)dst, 16, 0, 0);
        }
    };

    stage(0, 0);
    const int pswz = l31 << 4;
    const int glow = hi ^ ((l31 >> 3) & 3);
    const int goff0 = (l31 * 4 + glow) << 4;
    const int goff1 = goff0 ^ 32;
    int buf = 0;
    const int NT = M_ / 32;  // 49
    for (int t = 0; t < NT; t++) {
        if (t + 1 < NT) {
            stage(buf ^ 1, t + 1);
            asm volatile("s_waitcnt vmcnt(16)" ::: "memory");
        } else {
            asm volatile("s_waitcnt vmcnt(0)" ::: "memory");
        }
        blockbar();

        // ---- QK^T (swapped): each pha read feeds BOTH n-sets ----
        const char* phiB = (const char*)&phi_s[buf][0][0];
        float16v S0 = {}, S1 = {};
        __builtin_amdgcn_s_setprio(1);
#pragma unroll
        for (int kb = 0; kb < 16; kb++) {
            short8 pha = *(const short8*)(phiB + l31 * 512 + ((kb * 32 + hi * 16) ^ pswz));
            S0 = __builtin_amdgcn_mfma_f32_32x32x16_bf16(pha, q0[kb], S0, 0, 0, 0);
            S1 = __builtin_amdgcn_mfma_f32_32x32x16_bf16(pha, q1[kb], S1, 0, 0, 0);
        }
        __builtin_amdgcn_s_setprio(0);

        // ---- softmax numerator + pack, per set (limits live registers) ----
        union UF { unsigned int u[4]; short8 s; } pa0s0, pa1s0, pa0s1, pa1s1;
        {
            float p[16];
#pragma unroll
            for (int r = 0; r < 16; r++) { p[r] = exp2f(S0[r] * SCALE_LOG2E); rs0 += p[r]; }
            unsigned int k0, k1, k2, k3, k4, k5, k6, k7;
            asm("v_cvt_pk_bf16_f32 %0, %1, %2" : "=v"(k0) : "v"(p[0]),  "v"(p[1]));
            asm("v_cvt_pk_bf16_f32 %0, %1, %2" : "=v"(k1) : "v"(p[2]),  "v"(p[3]));
            asm("v_cvt_pk_bf16_f32 %0, %1, %2" : "=v"(k2) : "v"(p[4]),  "v"(p[5]));
            asm("v_cvt_pk_bf16_f32 %0, %1, %2" : "=v"(k3) : "v"(p[6]),  "v"(p[7]));
            asm("v_cvt_pk_bf16_f32 %0, %1, %2" : "=v"(k4) : "v"(p[8]),  "v"(p[9]));
            asm("v_cvt_pk_bf16_f32 %0, %1, %2" : "=v"(k5) : "v"(p[10]), "v"(p[11]));
            asm("v_cvt_pk_bf16_f32 %0, %1, %2" : "=v"(k6) : "v"(p[12]), "v"(p[13]));
            asm("v_cvt_pk_bf16_f32 %0, %1, %2" : "=v"(k7) : "v"(p[14]), "v"(p[15]));
            asm("v_permlane32_swap_b32 %0, %1" : "+v"(k0), "+v"(k2));
            asm("v_permlane32_swap_b32 %0, %1" : "+v"(k1), "+v"(k3));
            asm("v_permlane32_swap_b32 %0, %1" : "+v"(k4), "+v"(k6));
            asm("v_permlane32_swap_b32 %0, %1" : "+v"(k5), "+v"(k7));
            pa0s0.u[0] = k0; pa0s0.u[1] = k1; pa0s0.u[2] = k2; pa0s0.u[3] = k3;
            pa1s0.u[0] = k4; pa1s0.u[1] = k5; pa1s0.u[2] = k6; pa1s0.u[3] = k7;
        }
        {
            float p[16];
#pragma unroll
            for (int r = 0; r < 16; r++) { p[r] = exp2f(S1[r] * SCALE_LOG2E); rs1 += p[r]; }
            unsigned int k0, k1, k2, k3, k4, k5, k6, k7;
            asm("v_cvt_pk_bf16_f32 %0, %1, %2" : "=v"(k0) : "v"(p[0]),  "v"(p[1]));
            asm("v_cvt_pk_bf16_f32 %0, %1, %2" : "=v"(k1) : "v"(p[2]),  "v"(p[3]));
            asm("v_cvt_pk_bf16_f32 %0, %1, %2" : "=v"(k2) : "v"(p[4]),  "v"(p[5]));
            asm("v_cvt_pk_bf16_f32 %0, %1, %2" : "=v"(k3) : "v"(p[6]),  "v"(p[7]));
            asm("v_cvt_pk_bf16_f32 %0, %1, %2" : "=v"(k4) : "v"(p[8]),  "v"(p[9]));
            asm("v_cvt_pk_bf16_f32 %0, %1, %2" : "=v"(k5) : "v"(p[10]), "v"(p[11]));
            asm("v_cvt_pk_bf16_f32 %0, %1, %2" : "=v"(k6) : "v"(p[12]), "v"(p[13]));
            asm("v_cvt_pk_bf16_f32 %0, %1, %2" : "=v"(k7) : "v"(p[14]), "v"(p[15]));
            asm("v_permlane32_swap_b32 %0, %1" : "+v"(k0), "+v"(k2));
            asm("v_permlane32_swap_b32 %0, %1" : "+v"(k1), "+v"(k3));
            asm("v_permlane32_swap_b32 %0, %1" : "+v"(k4), "+v"(k6));
            asm("v_permlane32_swap_b32 %0, %1" : "+v"(k5), "+v"(k7));
            pa0s1.u[0] = k0; pa0s1.u[1] = k1; pa0s1.u[2] = k2; pa0s1.u[3] = k3;
            pa1s1.u[0] = k4; pa1s1.u[1] = k5; pa1s1.u[2] = k6; pa1s1.u[3] = k7;
        }

        // ---- PV: each gb read feeds BOTH n-sets ----
        const char* gB = (const char*)&g_s[buf][0];
        __builtin_amdgcn_s_setprio(1);
#pragma unroll
        for (int dblk = 0; dblk < 8; dblk++) {
            short8 gb0 = *(const short8*)(gB + dblk * 2048 + goff0);
            short8 gb1 = *(const short8*)(gB + dblk * 2048 + goff1);
            acc0[dblk] = __builtin_amdgcn_mfma_f32_32x32x16_bf16(pa0s0.s, gb0, acc0[dblk], 0, 0, 0);
            acc1[dblk] = __builtin_amdgcn_mfma_f32_32x32x16_bf16(pa0s1.s, gb0, acc1[dblk], 0, 0, 0);
            acc0[dblk] = __builtin_amdgcn_mfma_f32_32x32x16_bf16(pa1s0.s, gb1, acc0[dblk], 0, 0, 0);
            acc1[dblk] = __builtin_amdgcn_mfma_f32_32x32x16_bf16(pa1s1.s, gb1, acc1[dblk], 0, 0, 0);
        }
        __builtin_amdgcn_s_setprio(0);
        blockbar();
        buf ^= 1;
    }

    rs0 += __shfl_xor(rs0, 32, 64);
    rs1 += __shfl_xor(rs1, 32, 64);
    float inv0 = 1.0f / rs0;
    float inv1 = 1.0f / rs1;

#pragma unroll
    for (int set = 0; set < 2; set++) {
        unsigned short* OH = ttH + ((size_t)b * N_ + n0 + set * 32) * DI_;
        unsigned short* OL = ttL + ((size_t)b * N_ + n0 + set * 32) * DI_;
        float inv = set ? inv1 : inv0;
#pragma unroll
        for (int reg = 0; reg < 16; reg++) {
            int n_l = (reg & 3) + 8 * (reg >> 2) + 4 * hi;
            float invn = __shfl(inv, n_l, 64);
#pragma unroll
            for (int dblk = 0; dblk < 8; dblk++) {
                float v = (set ? acc1[dblk][reg] : acc0[dblk][reg]) * invn;
                unsigned short h = f2bf(v);
                unsigned short l = f2bf(v - bf2f(h));
                size_t idx = (size_t)n_l * DI_ + dblk * 32 + l31;
                OH[idx] = h;
                OL[idx] = l;
            }
        }
    }
}

// ---------- BN finalize ----------
__global__ void bn_finalize(const float* __restrict__ psum, float* __restrict__ stats) {
    int o = blockIdx.x;
    float s = 0.f, q = 0.f;
    for (int c = threadIdx.x; c < PSUM_COLS; c += 256) {
        s += psum[(size_t)o * PSUM_COLS + c];
        q += psum[(size_t)(DO_ + o) * PSUM_COLS + c];
    }
#pragma unroll
    for (int m = 1; m < 64; m <<= 1) { s += __shfl_xor(s, m, 64); q += __shfl_xor(q, m, 64); }
    __shared__ float ws1[4], ws2[4];
    int wave = threadIdx.x >> 6;
    if ((threadIdx.x & 63) == 0) { ws1[wave] = s; ws2[wave] = q; }
    __syncthreads();
    if (threadIdx.x == 0) {
        double S = (double)ws1[0] + ws1[1] + ws1[2] + ws1[3];
        double Q = (double)ws2[0] + ws2[1] + ws2[2] + ws2[3];
        const double cnt = (double)(B_ * N_);
        double mean = S / cnt;
        double var = Q / cnt - mean * mean;
        stats[o] = (float)mean;
        stats[DO_ + o] = (float)(1.0 / sqrt(var + (double)BN_EPS));
    }
}

// ---------- BN apply + residual: reads int16 fixed-point pre-BN out ----------
__global__ void bn_apply(const unsigned short* __restrict__ ob, const float* __restrict__ x,
                         const float* __restrict__ stats, const float* __restrict__ gamma,
                         const float* __restrict__ beta, float* __restrict__ out) {
    size_t i = ((size_t)blockIdx.x * 256 + threadIdx.x) * 8;
    short8 v8 = *(const short8*)(ob + i);
    int o = (int)((i / N_) % DO_);
    float mean = stats[o], rsig = stats[DO_ + o];
    float ga = gamma[o], be = beta[o];
    float4v x0 = *(const float4v*)(x + i);
    float4v x1 = *(const float4v*)(x + i + 4);
    float4v r0, r1;
#pragma unroll
    for (int j = 0; j < 4; j++) {
        r0[j] = ((float)(short)v8[j] * Q_INV - mean) * rsig * ga + be + x0[j];
        r1[j] = ((float)(short)v8[4 + j] * Q_INV - mean) * rsig * ga + be + x1[j];
    }
    *(float4v*)(out + i) = r0;
    *(float4v*)(out + i + 4) = r1;
}

extern "C" void kernel_launch(void* const* d_in, const int* in_sizes, int n_in,
                              void* d_out, int out_size, void* d_ws, size_t ws_size,
                              hipStream_t stream) {
    const float* x       = (const float*)d_in[0];
    const float* theta_w = (const float*)d_in[1];
    const float* theta_b = (const float*)d_in[2];
    const float* phi_w   = (const float*)d_in[3];
    const float* phi_b   = (const float*)d_in[4];
    const float* g_w     = (const float*)d_in[5];
    const float* g_b     = (const float*)d_in[6];
    const float* out_w   = (const float*)d_in[7];
    const float* out_b   = (const float*)d_in[8];
    const float* bn_g    = (const float*)d_in[9];
    const float* bn_b    = (const float*)d_in[10];
    float* out = (float*)d_out;

    char* ws = (char*)d_ws;
    size_t off = 0;
    auto alloc = [&](size_t bytes) { void* p = ws + off; off += (bytes + 255) & ~(size_t)255; return p; };
    unsigned short* xT     = (unsigned short*)alloc((size_t)B_ * N_ * C_ * 2);
    unsigned short* mpT    = (unsigned short*)alloc((size_t)B_ * M_ * C_ * 2);
    unsigned short* thetaT = (unsigned short*)alloc((size_t)B_ * N_ * DI_ * 2);
    unsigned short* phiT   = (unsigned short*)alloc((size_t)B_ * PG_BS * 2);   // padded
    unsigned short* gbuf   = (unsigned short*)alloc((size_t)B_ * PG_BS * 2);   // padded
    unsigned short* wq     = (unsigned short*)alloc((size_t)DI_ * C_ * 2);
    unsigned short* wp     = (unsigned short*)alloc((size_t)DI_ * C_ * 2);
    unsigned short* wg     = (unsigned short*)alloc((size_t)DI_ * C_ * 2);
    unsigned short* wo     = (unsigned short*)alloc((size_t)DO_ * DI_ * 2);
    float* stats           = (float*)alloc((size_t)DO_ * 2 * 4);
    float* psum            = (float*)alloc((size_t)DO_ * 2 * PSUM_COLS * 4);
    unsigned short* ttH    = xT;                               // xT dead after theta
    unsigned short* ttL    = xT + (size_t)B_ * N_ * DI_;
    unsigned short* out_q  = mpT;  // mpT..gbuf region dead after attn

    cast_w4<<<dim3(512, 4), 256, 0, stream>>>(theta_w, phi_w, g_w, out_w, wq, wp, wg, wo);

    xpose_x<<<dim3(N_ / 64, C_ / 64, B_), 256, 0, stream>>>(x, xT);
    pool_from_xT<<<dim3(M_, B_), 256, 0, stream>>>(xT, mpT);

    proj_gemm<0><<<392, 256, 0, stream>>>(xT, N_, wq, thetaT, (size_t)N_ * DI_, theta_b);
    proj_gemm<0><<<104, 256, 0, stream>>>(mpT, M_, wp, phiT, (size_t)PG_BS, phi_b);
    proj_gemm<1><<<104, 256, 0, stream>>>(mpT, M_, wg, gbuf, (size_t)PG_BS, g_b);

    attn_k<<<dim3((N_ / 128) * 8), 128, 0, stream>>>(thetaT, phiT, gbuf, ttH, ttL);

    out_gemm<<<1568, 256, 0, stream>>>(wo, ttH, ttL, out_q, out_b, psum);

    bn_finalize<<<DO_, 256, 0, stream>>>(psum, stats);
    bn_apply<<<(size_t)B_ * DO_ * N_ / 8 / 256, 256, 0, stream>>>(out_q, x, stats, bn_g, bn_b, out);
}

// Round 12
// 311.473 us; speedup vs baseline: 1.1438x; 1.1438x over previous
//
#include <hip/hip_runtime.h>
#include <hip/hip_bf16.h>

#define B_ 8
#define C_ 512
#define T_ 8
#define H_ 28
#define W_ 28
#define N_ (T_*H_*W_)   // 6272
#define HP_ 14
#define WP_ 14
#define M_ (T_*HP_*WP_) // 1568
#define DI_ 256
#define DO_ 512
#define BN_EPS 1e-5f
#define SCALE_LOG2E 0.090168440055560214f  // (1/sqrt(256)) * log2(e)
#define PSUM_COLS 392                       // 8 batch * 49 nchunk
#define PG_BS 425984                        // padded per-batch stride (shorts): 1664*256 == 52*8192
#define Q_SCALE 32768.0f
#define Q_INV   3.0517578125e-05f

typedef __attribute__((ext_vector_type(8))) short short8;
typedef __attribute__((ext_vector_type(4))) short short4v;
typedef __attribute__((ext_vector_type(4))) float float4v;
typedef __attribute__((ext_vector_type(16))) float float16v;
typedef __attribute__((ext_vector_type(2))) float float2v;

__device__ inline unsigned short f2bf(float f) {
    union { float f; unsigned int u; } v; v.f = f;
    unsigned int u = v.u;
    return (unsigned short)((u + 0x7FFFu + ((u >> 16) & 1u)) >> 16);
}
__device__ inline float bf2f(unsigned short h) {
    union { unsigned int u; float f; } v; v.u = ((unsigned int)h) << 16;
    return v.f;
}
// raw barrier: does NOT drain vmcnt (unlike __syncthreads)
__device__ inline void blockbar() {
    asm volatile("" ::: "memory");
    __builtin_amdgcn_s_barrier();
    asm volatile("" ::: "memory");
}

// ---------- transpose + cast x [C,N] f32 -> xT [N,C] bf16 (per b) ----------
__global__ void xpose_x(const float* __restrict__ x, unsigned short* __restrict__ xT) {
    __shared__ float tile[64][65];
    int b = blockIdx.z;
    int c0 = blockIdx.y * 64, n0 = blockIdx.x * 64;
    const float* src = x + (size_t)b * C_ * N_;
    int tx = threadIdx.x & 63, ty = threadIdx.x >> 6;
#pragma unroll
    for (int i = 0; i < 16; i++) {
        int c = ty + i * 4;
        tile[c][tx] = src[(size_t)(c0 + c) * N_ + n0 + tx];
    }
    __syncthreads();
    unsigned short* d = xT + ((size_t)b * N_ + n0) * C_ + c0;
#pragma unroll
    for (int i = 0; i < 16; i++) {
        int n = ty + i * 4;
        d[(size_t)n * C_ + tx] = f2bf(tile[tx][n]);
    }
}

// ---------- maxpool(1,2,2) from xT: mpT[b][p][c] = max of 4 xT rows ----------
// max is monotone: max of bf16-rounded == bf16-round of max -> bitwise identical to old path.
__global__ void pool_from_xT(const unsigned short* __restrict__ xT, unsigned short* __restrict__ mpT) {
    int b = blockIdx.y;
    int p = blockIdx.x;                     // 0..1567
    int t = p / 196, pp = p - t * 196;
    int hp = pp / 14, wp = pp - hp * 14;
    int n00 = t * 784 + (2 * hp) * 28 + 2 * wp;
    const unsigned short* r0 = xT + ((size_t)b * N_ + n00) * C_;
    int c = threadIdx.x * 2;
    unsigned int a = *(const unsigned int*)(r0 + c);
    unsigned int bb = *(const unsigned int*)(r0 + C_ + c);
    unsigned int cc = *(const unsigned int*)(r0 + 28 * C_ + c);
    unsigned int dd = *(const unsigned int*)(r0 + 29 * C_ + c);
    float lo = fmaxf(fmaxf(bf2f(a & 0xFFFF), bf2f(bb & 0xFFFF)),
                     fmaxf(bf2f(cc & 0xFFFF), bf2f(dd & 0xFFFF)));
    float hi = fmaxf(fmaxf(bf2f(a >> 16), bf2f(bb >> 16)),
                     fmaxf(bf2f(cc >> 16), bf2f(dd >> 16)));
    unsigned int r = (unsigned int)f2bf(lo) | ((unsigned int)f2bf(hi) << 16);
    *(unsigned int*)(mpT + ((size_t)b * M_ + p) * C_ + c) = r;
}

// ---------- cast all 4 weight arrays (each 131072 elems) ----------
__global__ void cast_w4(const float* __restrict__ a0, const float* __restrict__ a1,
                        const float* __restrict__ a2, const float* __restrict__ a3,
                        unsigned short* __restrict__ d0, unsigned short* __restrict__ d1,
                        unsigned short* __restrict__ d2, unsigned short* __restrict__ d3) {
    int i = blockIdx.x * 256 + threadIdx.x;
    const float* s; unsigned short* d;
    switch (blockIdx.y) {
        case 0: s = a0; d = d0; break;
        case 1: s = a1; d = d1; break;
        case 2: s = a2; d = d2; break;
        default: s = a3; d = d3; break;
    }
    d[i] = f2bf(s[i]);
}

// ---------- unified projection GEMM (theta/phi/g), LDS-staged, raw barriers ----------
template<int GL>
__global__ __launch_bounds__(256, 2) void proj_gemm(
        const unsigned short* __restrict__ A, int MR,
        const unsigned short* __restrict__ W,
        unsigned short* __restrict__ Dp, size_t dBatch,
        const float* __restrict__ bias) {
    __shared__ __align__(16) unsigned short wqs[2][32][512];   // 64KB
    __shared__ __align__(16) unsigned short gscr[GL ? 4096 : 4];
    const int bid = blockIdx.x;
    const int b = bid & 7;
    const int nblk = bid >> 3;
    const int wave = threadIdx.x >> 6, lane = threadIdx.x & 63;
    const int lr = lane & 15, lk = lane >> 4;
    const unsigned short* Ab = A + (size_t)b * MR * C_;
    const int rbase = nblk * 128 + wave * 32;

    short8 a[2][16];
#pragma unroll
    for (int i = 0; i < 2; i++) {
        int row = rbase + i * 16 + lr; if (row >= MR) row = MR - 1;
#pragma unroll
        for (int kd = 0; kd < 16; kd++)
            a[i][kd] = *(const short8*)(Ab + (size_t)row * C_ + kd * 32 + lk * 8);
    }

    auto stage = [&](int bufi, int t) {
#pragma unroll
        for (int j = 0; j < 8; j++) {
            int row = wave * 8 + j;
            int qq = (lane * 16) ^ ((row & 7) << 4);
            const unsigned short* src = W + (size_t)(t * 32 + row) * C_ + (qq >> 1);
            unsigned short* dst = &wqs[bufi][0][0] + row * 512;
            __builtin_amdgcn_global_load_lds(
                (const __attribute__((address_space(1))) unsigned int*)src,
                (__attribute__((address_space(3))) unsigned int*)dst, 16, 0, 0);
        }
    };

    stage(0, 0);
    const int hq = (lk * 16) ^ ((lr & 7) << 4);
    unsigned short* Dlin = Dp + (size_t)b * dBatch + (size_t)rbase * DI_;
    unsigned short* Dg = Dp + (size_t)b * dBatch;
    int buf = 0;
#pragma unroll
    for (int t = 0; t < 8; t++) {
        if (t < 7) {
            stage(buf ^ 1, t + 1);
            if (t == 0) { asm volatile("s_waitcnt vmcnt(8)" ::: "memory"); }
            else if (GL == 0) { asm volatile("s_waitcnt vmcnt(24)" ::: "memory"); }
            else { asm volatile("s_waitcnt vmcnt(10)" ::: "memory"); }
        } else {
            if (GL == 0) { asm volatile("s_waitcnt vmcnt(16)" ::: "memory"); }
            else { asm volatile("s_waitcnt vmcnt(2)" ::: "memory"); }
        }
        blockbar();
        const char* Wb = (const char*)&wqs[buf][0][0];
        float4v acc[2][2] = {};
#pragma unroll
        for (int kd = 0; kd < 16; kd++) {
            short8 b0 = *(const short8*)(Wb + lr * 1024 + ((kd * 64) ^ hq));
            short8 b1 = *(const short8*)(Wb + (16 + lr) * 1024 + ((kd * 64) ^ hq));
            acc[0][0] = __builtin_amdgcn_mfma_f32_16x16x32_bf16(a[0][kd], b0, acc[0][0], 0, 0, 0);
            acc[0][1] = __builtin_amdgcn_mfma_f32_16x16x32_bf16(a[0][kd], b1, acc[0][1], 0, 0, 0);
            acc[1][0] = __builtin_amdgcn_mfma_f32_16x16x32_bf16(a[1][kd], b0, acc[1][0], 0, 0, 0);
            acc[1][1] = __builtin_amdgcn_mfma_f32_16x16x32_bf16(a[1][kd], b1, acc[1][1], 0, 0, 0);
        }
        if (GL == 0) {
#pragma unroll
            for (int i = 0; i < 2; i++)
#pragma unroll
                for (int j = 0; j < 2; j++) {
                    int col = t * 32 + j * 16 + lr;
                    float bv = bias[col];
#pragma unroll
                    for (int r = 0; r < 4; r++) {
                        int row = i * 16 + lk * 4 + r;
                        Dlin[(size_t)row * DI_ + col] = f2bf(acc[i][j][r] + bv);
                    }
                }
        } else {
#pragma unroll
            for (int i = 0; i < 2; i++) {
                int sm = (i * 2 + (lk >> 1)) & 3;
#pragma unroll
                for (int j = 0; j < 2; j++) {
                    int dd = j * 16 + lr;
                    int slot = dd * 4 + (sm ^ ((dd >> 3) & 3));
                    float bv = bias[t * 32 + dd];
                    short4v pk;
#pragma unroll
                    for (int r = 0; r < 4; r++) pk[r] = (short)f2bf(acc[i][j][r] + bv);
                    *(short4v*)(&gscr[wave * 1024 + slot * 8 + (lk & 1) * 4]) = pk;
                }
            }
            asm volatile("s_waitcnt lgkmcnt(0)" ::: "memory");
            blockbar();
#pragma unroll
            for (int r2 = 0; r2 < 2; r2++) {
                int idx = r2 * 256 + threadIdx.x;
                int w = idx >> 7;
                int o2 = (idx * 8) & 1023;
                short8 v = *(const short8*)(&gscr[idx * 8]);
                *(short8*)(Dg + (size_t)(nblk * 4 + w) * 8192 + t * 1024 + o2) = v;
            }
        }
        blockbar();
        buf ^= 1;
    }
}

// ---------- out GEMM, LDS-staged, int16 fixed-point output + fused BN partial sums ----------
__global__ __launch_bounds__(256, 2) void out_gemm(
        const unsigned short* __restrict__ wo,
        const unsigned short* __restrict__ Bh, const unsigned short* __restrict__ Bl,
        unsigned short* __restrict__ Dp, const float* __restrict__ bias,
        float* __restrict__ psum) {
    __shared__ __align__(16) unsigned short tts[2][2][32][256];  // 64KB
    const int bid = blockIdx.x;
    const int b = bid & 7;
    const int rem = bid >> 3;
    const int doblk = rem & 3;
    const int nchunk = rem >> 2;
    const int wave = threadIdx.x >> 6, lane = threadIdx.x & 63;
    const int lr = lane & 15, lk = lane >> 4;
    const unsigned short* Ab = wo + (size_t)(doblk * 128 + wave * 32) * DI_;
    const unsigned short* BhB = Bh + ((size_t)b * N_ + nchunk * 128) * DI_;
    const unsigned short* BlB = Bl + ((size_t)b * N_ + nchunk * 128) * DI_;

    short8 a[2][8];
#pragma unroll
    for (int i = 0; i < 2; i++)
#pragma unroll
        for (int kd = 0; kd < 8; kd++)
            a[i][kd] = *(const short8*)(Ab + (size_t)(i * 16 + lr) * DI_ + kd * 32 + lk * 8);

    auto stage = [&](int bufi, int t) {
#pragma unroll
        for (int p = 0; p < 2; p++) {
            const unsigned short* S = p ? BlB : BhB;
#pragma unroll
            for (int j = 0; j < 4; j++) {
                int chunk = wave * 4 + j;
                int row = chunk * 2 + (lane >> 5);
                int qq = (((lane & 31) * 16)) ^ ((row & 7) << 4);
                const unsigned short* src = S + (size_t)(t * 32 + row) * DI_ + (qq >> 1);
                unsigned short* dst = &tts[bufi][p][0][0] + chunk * 512;
                __builtin_amdgcn_global_load_lds(
                    (const __attribute__((address_space(1))) unsigned int*)src,
                    (__attribute__((address_space(3))) unsigned int*)dst, 16, 0, 0);
            }
        }
    };

    stage(0, 0);
    const int hq = (lk * 16) ^ ((lr & 7) << 4);
    float4v acc[4][2][2] = {};
    int buf = 0;
#pragma unroll
    for (int t = 0; t < 4; t++) {
        if (t < 3) {
            stage(buf ^ 1, t + 1);
            asm volatile("s_waitcnt vmcnt(8)" ::: "memory");
        } else {
            asm volatile("s_waitcnt vmcnt(0)" ::: "memory");
        }
        blockbar();
        const char* th = (const char*)&tts[buf][0][0][0];
        const char* tl = (const char*)&tts[buf][1][0][0];
#pragma unroll
        for (int kd = 0; kd < 8; kd++) {
            short8 bh0 = *(const short8*)(th + lr * 512 + ((kd * 64) ^ hq));
            short8 bh1 = *(const short8*)(th + (16 + lr) * 512 + ((kd * 64) ^ hq));
            short8 bl0 = *(const short8*)(tl + lr * 512 + ((kd * 64) ^ hq));
            short8 bl1 = *(const short8*)(tl + (16 + lr) * 512 + ((kd * 64) ^ hq));
            acc[t][0][0] = __builtin_amdgcn_mfma_f32_16x16x32_bf16(a[0][kd], bh0, acc[t][0][0], 0, 0, 0);
            acc[t][0][0] = __builtin_amdgcn_mfma_f32_16x16x32_bf16(a[0][kd], bl0, acc[t][0][0], 0, 0, 0);
            acc[t][0][1] = __builtin_amdgcn_mfma_f32_16x16x32_bf16(a[0][kd], bh1, acc[t][0][1], 0, 0, 0);
            acc[t][0][1] = __builtin_amdgcn_mfma_f32_16x16x32_bf16(a[0][kd], bl1, acc[t][0][1], 0, 0, 0);
            acc[t][1][0] = __builtin_amdgcn_mfma_f32_16x16x32_bf16(a[1][kd], bh0, acc[t][1][0], 0, 0, 0);
            acc[t][1][0] = __builtin_amdgcn_mfma_f32_16x16x32_bf16(a[1][kd], bl0, acc[t][1][0], 0, 0, 0);
            acc[t][1][1] = __builtin_amdgcn_mfma_f32_16x16x32_bf16(a[1][kd], bh1, acc[t][1][1], 0, 0, 0);
            acc[t][1][1] = __builtin_amdgcn_mfma_f32_16x16x32_bf16(a[1][kd], bl1, acc[t][1][1], 0, 0, 0);
        }
        blockbar();
        buf ^= 1;
    }
    unsigned short* Db = Dp + (size_t)b * DO_ * N_;
    float s1[2][4] = {}, s2[2][4] = {};
#pragma unroll
    for (int t = 0; t < 4; t++)
#pragma unroll
        for (int i = 0; i < 2; i++)
#pragma unroll
            for (int r = 0; r < 4; r++) {
                int dorow = doblk * 128 + wave * 32 + i * 16 + lk * 4 + r;
                float bv = bias[dorow];
                float v0 = acc[t][i][0][r] + bv;
                float v1 = acc[t][i][1][r] + bv;
                int ncol = nchunk * 128 + t * 32 + lr;
                float c0 = fminf(fmaxf(v0 * Q_SCALE, -32767.f), 32767.f);
                float c1 = fminf(fmaxf(v1 * Q_SCALE, -32767.f), 32767.f);
                Db[(size_t)dorow * N_ + ncol] = (unsigned short)(short)lrintf(c0);
                Db[(size_t)dorow * N_ + ncol + 16] = (unsigned short)(short)lrintf(c1);
                s1[i][r] += v0 + v1;
                s2[i][r] += v0 * v0 + v1 * v1;
            }
#pragma unroll
    for (int m = 1; m < 16; m <<= 1)
#pragma unroll
        for (int i = 0; i < 2; i++)
#pragma unroll
            for (int r = 0; r < 4; r++) {
                s1[i][r] += __shfl_xor(s1[i][r], m, 64);
                s2[i][r] += __shfl_xor(s2[i][r], m, 64);
            }
    if (lr == 0) {
        int pcol = b * 49 + nchunk;
#pragma unroll
        for (int i = 0; i < 2; i++)
#pragma unroll
            for (int r = 0; r < 4; r++) {
                int row = doblk * 128 + wave * 32 + i * 16 + lk * 4 + r;
                psum[(size_t)row * PSUM_COLS + pcol] = s1[i][r];
                psum[(size_t)(DO_ + row) * PSUM_COLS + pcol] = s2[i][r];
            }
    }
}

// ---------- fused attention (round-10 structure: 4 waves, 32 q-rows/wave) ----------
__global__ __launch_bounds__(256, 2) void attn_k(
        const unsigned short* __restrict__ thetaT,
        const unsigned short* __restrict__ phiT,
        const unsigned short* __restrict__ g,
        unsigned short* __restrict__ ttH,
        unsigned short* __restrict__ ttL) {
    __shared__ __align__(16) unsigned short phi_s[2][32][256];  // 32KB
    __shared__ __align__(16) unsigned short g_s[2][8192];       // 32KB
    const int bid = blockIdx.x;
    const int b = bid & 7;
    const int nblk = bid >> 3;
    const int wave = threadIdx.x >> 6, lane = threadIdx.x & 63;
    const int l31 = lane & 31, hi = lane >> 5;
    const int n0 = nblk * 128 + wave * 32;
    const unsigned short* Q  = thetaT + ((size_t)b * N_ + n0) * DI_;
    const unsigned short* Pg = phiT + (size_t)b * PG_BS;
    const unsigned short* G  = g + (size_t)b * PG_BS;

    short8 q[16];
#pragma unroll
    for (int kb = 0; kb < 16; kb++)
        q[kb] = *(const short8*)(Q + (size_t)l31 * DI_ + kb * 16 + hi * 8);

    float16v acc[8] = {};
    float rs = 0.f;

    auto stage = [&](int bufi, int t) {
        const unsigned short* phiRow = Pg + (size_t)t * 32 * DI_;
#pragma unroll
        for (int j = 0; j < 4; j++) {
            int chunk = wave * 4 + j;
            int row = chunk * 2 + (lane >> 5);
            int qq = ((lane & 31) * 16) ^ ((row & 31) << 4);
            const unsigned short* src = phiRow + (size_t)row * DI_ + (qq >> 1);
            unsigned short* dst = &phi_s[bufi][0][0] + chunk * 512;
            __builtin_amdgcn_global_load_lds(
                (const __attribute__((address_space(1))) unsigned int*)src,
                (__attribute__((address_space(3))) unsigned int*)dst, 16, 0, 0);
        }
        const unsigned short* Gt = G + (size_t)t * 8192;
#pragma unroll
        for (int j = 0; j < 4; j++) {
            int chunk = wave * 4 + j;
            const unsigned short* src = Gt + chunk * 512 + lane * 8;
            unsigned short* dst = &g_s[bufi][0] + chunk * 512;
            __builtin_amdgcn_global_load_lds(
                (const __attribute__((address_space(1))) unsigned int*)src,
                (__attribute__((address_space(3))) unsigned int*)dst, 16, 0, 0);
        }
    };

    stage(0, 0);
    const int pswz = l31 << 4;
    const int glow = hi ^ ((l31 >> 3) & 3);
    const int goff0 = (l31 * 4 + glow) << 4;
    const int goff1 = goff0 ^ 32;
    int buf = 0;
    const int NT = M_ / 32;  // 49
    for (int t = 0; t < NT; t++) {
        if (t + 1 < NT) {
            stage(buf ^ 1, t + 1);
            asm volatile("s_waitcnt vmcnt(8)" ::: "memory");
        } else {
            asm volatile("s_waitcnt vmcnt(0)" ::: "memory");
        }
        blockbar();

        const char* phiB = (const char*)&phi_s[buf][0][0];
        float16v S0 = {}, S1 = {};
        __builtin_amdgcn_s_setprio(1);
#pragma unroll
        for (int kb = 0; kb < 8; kb++) {
            short8 pha0 = *(const short8*)(phiB + l31 * 512 + ((kb * 32 + hi * 16) ^ pswz));
            short8 pha1 = *(const short8*)(phiB + l31 * 512 + (((kb + 8) * 32 + hi * 16) ^ pswz));
            S0 = __builtin_amdgcn_mfma_f32_32x32x16_bf16(pha0, q[kb], S0, 0, 0, 0);
            S1 = __builtin_amdgcn_mfma_f32_32x32x16_bf16(pha1, q[kb + 8], S1, 0, 0, 0);
        }
        __builtin_amdgcn_s_setprio(0);

        float p[16];
#pragma unroll
        for (int r = 0; r < 16; r++) {
            p[r] = exp2f((S0[r] + S1[r]) * SCALE_LOG2E);
            rs += p[r];
        }
        unsigned int pk0, pk1, pk2, pk3, pk4, pk5, pk6, pk7;
        asm("v_cvt_pk_bf16_f32 %0, %1, %2" : "=v"(pk0) : "v"(p[0]),  "v"(p[1]));
        asm("v_cvt_pk_bf16_f32 %0, %1, %2" : "=v"(pk1) : "v"(p[2]),  "v"(p[3]));
        asm("v_cvt_pk_bf16_f32 %0, %1, %2" : "=v"(pk2) : "v"(p[4]),  "v"(p[5]));
        asm("v_cvt_pk_bf16_f32 %0, %1, %2" : "=v"(pk3) : "v"(p[6]),  "v"(p[7]));
        asm("v_cvt_pk_bf16_f32 %0, %1, %2" : "=v"(pk4) : "v"(p[8]),  "v"(p[9]));
        asm("v_cvt_pk_bf16_f32 %0, %1, %2" : "=v"(pk5) : "v"(p[10]), "v"(p[11]));
        asm("v_cvt_pk_bf16_f32 %0, %1, %2" : "=v"(pk6) : "v"(p[12]), "v"(p[13]));
        asm("v_cvt_pk_bf16_f32 %0, %1, %2" : "=v"(pk7) : "v"(p[14]), "v"(p[15]));
        asm("v_permlane32_swap_b32 %0, %1" : "+v"(pk0), "+v"(pk2));
        asm("v_permlane32_swap_b32 %0, %1" : "+v"(pk1), "+v"(pk3));
        asm("v_permlane32_swap_b32 %0, %1" : "+v"(pk4), "+v"(pk6));
        asm("v_permlane32_swap_b32 %0, %1" : "+v"(pk5), "+v"(pk7));
        union UF { unsigned int u[4]; short8 s; } pa0, pa1;
        pa0.u[0] = pk0; pa0.u[1] = pk1; pa0.u[2] = pk2; pa0.u[3] = pk3;
        pa1.u[0] = pk4; pa1.u[1] = pk5; pa1.u[2] = pk6; pa1.u[3] = pk7;

        const char* gB = (const char*)&g_s[buf][0];
        __builtin_amdgcn_s_setprio(1);
#pragma unroll
        for (int dblk = 0; dblk < 8; dblk++) {
            short8 gb0 = *(const short8*)(gB + dblk * 2048 + goff0);
            short8 gb1 = *(const short8*)(gB + dblk * 2048 + goff1);
            acc[dblk] = __builtin_amdgcn_mfma_f32_32x32x16_bf16(pa0.s, gb0, acc[dblk], 0, 0, 0);
            acc[dblk] = __builtin_amdgcn_mfma_f32_32x32x16_bf16(pa1.s, gb1, acc[dblk], 0, 0, 0);
        }
        __builtin_amdgcn_s_setprio(0);
        blockbar();
        buf ^= 1;
    }

    rs += __shfl_xor(rs, 32, 64);
    float inv = 1.0f / rs;

    unsigned short* OH = ttH + ((size_t)b * N_ + n0) * DI_;
    unsigned short* OL = ttL + ((size_t)b * N_ + n0) * DI_;
#pragma unroll
    for (int reg = 0; reg < 16; reg++) {
        int n_l = (reg & 3) + 8 * (reg >> 2) + 4 * hi;
        float invn = __shfl(inv, n_l, 64);
#pragma unroll
        for (int dblk = 0; dblk < 8; dblk++) {
            float v = acc[dblk][reg] * invn;
            unsigned short h = f2bf(v);
            unsigned short l = f2bf(v - bf2f(h));
            size_t idx = (size_t)n_l * DI_ + dblk * 32 + l31;
            OH[idx] = h;
            OL[idx] = l;
        }
    }
}

// ---------- BN finalize ----------
__global__ void bn_finalize(const float* __restrict__ psum, float* __restrict__ stats) {
    int o = blockIdx.x;
    float s = 0.f, q = 0.f;
    for (int c = threadIdx.x; c < PSUM_COLS; c += 256) {
        s += psum[(size_t)o * PSUM_COLS + c];
        q += psum[(size_t)(DO_ + o) * PSUM_COLS + c];
    }
#pragma unroll
    for (int m = 1; m < 64; m <<= 1) { s += __shfl_xor(s, m, 64); q += __shfl_xor(q, m, 64); }
    __shared__ float ws1[4], ws2[4];
    int wave = threadIdx.x >> 6;
    if ((threadIdx.x & 63) == 0) { ws1[wave] = s; ws2[wave] = q; }
    __syncthreads();
    if (threadIdx.x == 0) {
        double S = (double)ws1[0] + ws1[1] + ws1[2] + ws1[3];
        double Q = (double)ws2[0] + ws2[1] + ws2[2] + ws2[3];
        const double cnt = (double)(B_ * N_);
        double mean = S / cnt;
        double var = Q / cnt - mean * mean;
        stats[o] = (float)mean;
        stats[DO_ + o] = (float)(1.0 / sqrt(var + (double)BN_EPS));
    }
}

// ---------- BN apply + residual: reads int16 fixed-point pre-BN out ----------
__global__ void bn_apply(const unsigned short* __restrict__ ob, const float* __restrict__ x,
                         const float* __restrict__ stats, const float* __restrict__ gamma,
                         const float* __restrict__ beta, float* __restrict__ out) {
    size_t i = ((size_t)blockIdx.x * 256 + threadIdx.x) * 8;
    short8 v8 = *(const short8*)(ob + i);
    int o = (int)((i / N_) % DO_);
    float mean = stats[o], rsig = stats[DO_ + o];
    float ga = gamma[o], be = beta[o];
    float4v x0 = *(const float4v*)(x + i);
    float4v x1 = *(const float4v*)(x + i + 4);
    float4v r0, r1;
#pragma unroll
    for (int j = 0; j < 4; j++) {
        r0[j] = ((float)(short)v8[j] * Q_INV - mean) * rsig * ga + be + x0[j];
        r1[j] = ((float)(short)v8[4 + j] * Q_INV - mean) * rsig * ga + be + x1[j];
    }
    *(float4v*)(out + i) = r0;
    *(float4v*)(out + i + 4) = r1;
}

extern "C" void kernel_launch(void* const* d_in, const int* in_sizes, int n_in,
                              void* d_out, int out_size, void* d_ws, size_t ws_size,
                              hipStream_t stream) {
    const float* x       = (const float*)d_in[0];
    const float* theta_w = (const float*)d_in[1];
    const float* theta_b = (const float*)d_in[2];
    const float* phi_w   = (const float*)d_in[3];
    const float* phi_b   = (const float*)d_in[4];
    const float* g_w     = (const float*)d_in[5];
    const float* g_b     = (const float*)d_in[6];
    const float* out_w   = (const float*)d_in[7];
    const float* out_b   = (const float*)d_in[8];
    const float* bn_g    = (const float*)d_in[9];
    const float* bn_b    = (const float*)d_in[10];
    float* out = (float*)d_out;

    char* ws = (char*)d_ws;
    size_t off = 0;
    auto alloc = [&](size_t bytes) { void* p = ws + off; off += (bytes + 255) & ~(size_t)255; return p; };
    unsigned short* xT     = (unsigned short*)alloc((size_t)B_ * N_ * C_ * 2);
    unsigned short* mpT    = (unsigned short*)alloc((size_t)B_ * M_ * C_ * 2);
    unsigned short* thetaT = (unsigned short*)alloc((size_t)B_ * N_ * DI_ * 2);
    unsigned short* phiT   = (unsigned short*)alloc((size_t)B_ * PG_BS * 2);   // padded
    unsigned short* gbuf   = (unsigned short*)alloc((size_t)B_ * PG_BS * 2);   // padded
    unsigned short* wq     = (unsigned short*)alloc((size_t)DI_ * C_ * 2);
    unsigned short* wp     = (unsigned short*)alloc((size_t)DI_ * C_ * 2);
    unsigned short* wg     = (unsigned short*)alloc((size_t)DI_ * C_ * 2);
    unsigned short* wo     = (unsigned short*)alloc((size_t)DO_ * DI_ * 2);
    float* stats           = (float*)alloc((size_t)DO_ * 2 * 4);
    float* psum            = (float*)alloc((size_t)DO_ * 2 * PSUM_COLS * 4);
    unsigned short* ttH    = xT;                               // xT dead after theta
    unsigned short* ttL    = xT + (size_t)B_ * N_ * DI_;
    unsigned short* out_q  = mpT;  // mpT..gbuf region dead after attn

    cast_w4<<<dim3(512, 4), 256, 0, stream>>>(theta_w, phi_w, g_w, out_w, wq, wp, wg, wo);

    xpose_x<<<dim3(N_ / 64, C_ / 64, B_), 256, 0, stream>>>(x, xT);
    pool_from_xT<<<dim3(M_, B_), 256, 0, stream>>>(xT, mpT);

    proj_gemm<0><<<392, 256, 0, stream>>>(xT, N_, wq, thetaT, (size_t)N_ * DI_, theta_b);
    proj_gemm<0><<<104, 256, 0, stream>>>(mpT, M_, wp, phiT, (size_t)PG_BS, phi_b);
    proj_gemm<1><<<104, 256, 0, stream>>>(mpT, M_, wg, gbuf, (size_t)PG_BS, g_b);

    attn_k<<<dim3((N_ / 128) * 8), 256, 0, stream>>>(thetaT, phiT, gbuf, ttH, ttL);

    out_gemm<<<1568, 256, 0, stream>>>(wo, ttH, ttL, out_q, out_b, psum);

    bn_finalize<<<DO_, 256, 0, stream>>>(psum, stats);
    bn_apply<<<(size_t)B_ * DO_ * N_ / 8 / 256, 256, 0, stream>>>(out_q, x, stats, bn_g, bn_b, out);
}

// Round 13
// 310.733 us; speedup vs baseline: 1.1465x; 1.0024x over previous
//
#include <hip/hip_runtime.h>
#include <hip/hip_bf16.h>

#define B_ 8
#define C_ 512
#define T_ 8
#define H_ 28
#define W_ 28
#define N_ (T_*H_*W_)   // 6272
#define HP_ 14
#define WP_ 14
#define M_ (T_*HP_*WP_) // 1568
#define DI_ 256
#define DO_ 512
#define BN_EPS 1e-5f
#define SCALE_LOG2E 0.090168440055560214f  // (1/sqrt(256)) * log2(e)
#define PSUM_COLS 392                       // 8 batch * 49 nchunk
#define PG_BS 425984                        // padded per-batch stride (shorts): 1664*256 == 52*8192
#define Q_SCALE 32768.0f
#define Q_INV   3.0517578125e-05f

typedef __attribute__((ext_vector_type(8))) short short8;
typedef __attribute__((ext_vector_type(4))) short short4v;
typedef __attribute__((ext_vector_type(4))) float float4v;
typedef __attribute__((ext_vector_type(16))) float float16v;
typedef __attribute__((ext_vector_type(2))) float float2v;
typedef __attribute__((ext_vector_type(2))) unsigned int uint2v;

__device__ inline unsigned short f2bf(float f) {
    union { float f; unsigned int u; } v; v.f = f;
    unsigned int u = v.u;
    return (unsigned short)((u + 0x7FFFu + ((u >> 16) & 1u)) >> 16);
}
__device__ inline float bf2f(unsigned short h) {
    union { unsigned int u; float f; } v; v.u = ((unsigned int)h) << 16;
    return v.f;
}
// raw barrier: does NOT drain vmcnt (unlike __syncthreads)
__device__ inline void blockbar() {
    asm volatile("" ::: "memory");
    __builtin_amdgcn_s_barrier();
    asm volatile("" ::: "memory");
}

// ---------- transpose + cast x [C,N] f32 -> xT [N,C] bf16 (per b), vectorized ----------
__global__ void xpose_x(const float* __restrict__ x, unsigned short* __restrict__ xT) {
    __shared__ float tile[64][65];
    int b = blockIdx.z;
    int c0 = blockIdx.y * 64, n0 = blockIdx.x * 64;
    const float* src = x + (size_t)b * C_ * N_;
    int r = threadIdx.x >> 5;       // 0..7
    int col2 = threadIdx.x & 31;    // pair index
#pragma unroll
    for (int i = 0; i < 8; i++) {
        int c = i * 8 + r;
        float2v v = *(const float2v*)(src + (size_t)(c0 + c) * N_ + n0 + col2 * 2);
        tile[c][col2 * 2] = v.x;
        tile[c][col2 * 2 + 1] = v.y;
    }
    __syncthreads();
    unsigned short* d = xT + ((size_t)b * N_ + n0) * C_ + c0;
#pragma unroll
    for (int i = 0; i < 8; i++) {
        int n = i * 8 + r;
        unsigned int lo = f2bf(tile[col2 * 2][n]);
        unsigned int hi = f2bf(tile[col2 * 2 + 1][n]);
        *(unsigned int*)(d + (size_t)n * C_ + col2 * 2) = lo | (hi << 16);
    }
}

// ---------- maxpool(1,2,2) from xT, vectorized (uint2 = 4 bf16 per lane) ----------
__global__ void pool_from_xT(const unsigned short* __restrict__ xT, unsigned short* __restrict__ mpT) {
    int b = blockIdx.y;
    int p = blockIdx.x * 2 + (threadIdx.x >> 7);   // 784*2 = 1568 outputs
    int tid = threadIdx.x & 127;
    int t = p / 196, pp = p - t * 196;
    int hp = pp / 14, wp = pp - hp * 14;
    int n00 = t * 784 + (2 * hp) * 28 + 2 * wp;
    const unsigned short* r0 = xT + ((size_t)b * N_ + n00) * C_;
    int c = tid * 4;
    uint2v a = *(const uint2v*)(r0 + c);
    uint2v bb = *(const uint2v*)(r0 + C_ + c);
    uint2v cc = *(const uint2v*)(r0 + 28 * C_ + c);
    uint2v dd = *(const uint2v*)(r0 + 29 * C_ + c);
    uint2v res;
#pragma unroll
    for (int j = 0; j < 2; j++) {
        float lo = fmaxf(fmaxf(bf2f(a[j] & 0xFFFF), bf2f(bb[j] & 0xFFFF)),
                         fmaxf(bf2f(cc[j] & 0xFFFF), bf2f(dd[j] & 0xFFFF)));
        float hi = fmaxf(fmaxf(bf2f(a[j] >> 16), bf2f(bb[j] >> 16)),
                         fmaxf(bf2f(cc[j] >> 16), bf2f(dd[j] >> 16)));
        res[j] = (unsigned int)f2bf(lo) | ((unsigned int)f2bf(hi) << 16);
    }
    *(uint2v*)(mpT + ((size_t)b * M_ + p) * C_ + c) = res;
}

// ---------- cast all 4 weight arrays (each 131072 elems) ----------
__global__ void cast_w4(const float* __restrict__ a0, const float* __restrict__ a1,
                        const float* __restrict__ a2, const float* __restrict__ a3,
                        unsigned short* __restrict__ d0, unsigned short* __restrict__ d1,
                        unsigned short* __restrict__ d2, unsigned short* __restrict__ d3) {
    int i = blockIdx.x * 256 + threadIdx.x;
    const float* s; unsigned short* d;
    switch (blockIdx.y) {
        case 0: s = a0; d = d0; break;
        case 1: s = a1; d = d1; break;
        case 2: s = a2; d = d2; break;
        default: s = a3; d = d3; break;
    }
    d[i] = f2bf(s[i]);
}

// ---------- unified projection GEMM (theta/phi/g), LDS-staged, raw barriers ----------
template<int GL>
__global__ __launch_bounds__(256, 2) void proj_gemm(
        const unsigned short* __restrict__ A, int MR,
        const unsigned short* __restrict__ W,
        unsigned short* __restrict__ Dp, size_t dBatch,
        const float* __restrict__ bias) {
    __shared__ __align__(16) unsigned short wqs[2][32][512];   // 64KB
    __shared__ __align__(16) unsigned short gscr[GL ? 4096 : 4];
    const int bid = blockIdx.x;
    const int b = bid & 7;
    const int nblk = bid >> 3;
    const int wave = threadIdx.x >> 6, lane = threadIdx.x & 63;
    const int lr = lane & 15, lk = lane >> 4;
    const unsigned short* Ab = A + (size_t)b * MR * C_;
    const int rbase = nblk * 128 + wave * 32;

    short8 a[2][16];
#pragma unroll
    for (int i = 0; i < 2; i++) {
        int row = rbase + i * 16 + lr; if (row >= MR) row = MR - 1;
#pragma unroll
        for (int kd = 0; kd < 16; kd++)
            a[i][kd] = *(const short8*)(Ab + (size_t)row * C_ + kd * 32 + lk * 8);
    }

    auto stage = [&](int bufi, int t) {
#pragma unroll
        for (int j = 0; j < 8; j++) {
            int row = wave * 8 + j;
            int qq = (lane * 16) ^ ((row & 7) << 4);
            const unsigned short* src = W + (size_t)(t * 32 + row) * C_ + (qq >> 1);
            unsigned short* dst = &wqs[bufi][0][0] + row * 512;
            __builtin_amdgcn_global_load_lds(
                (const __attribute__((address_space(1))) unsigned int*)src,
                (__attribute__((address_space(3))) unsigned int*)dst, 16, 0, 0);
        }
    };

    stage(0, 0);
    const int hq = (lk * 16) ^ ((lr & 7) << 4);
    unsigned short* Dlin = Dp + (size_t)b * dBatch + (size_t)rbase * DI_;
    unsigned short* Dg = Dp + (size_t)b * dBatch;
    int buf = 0;
#pragma unroll
    for (int t = 0; t < 8; t++) {
        if (t < 7) {
            stage(buf ^ 1, t + 1);
            if (t == 0) { asm volatile("s_waitcnt vmcnt(8)" ::: "memory"); }
            else if (GL == 0) { asm volatile("s_waitcnt vmcnt(24)" ::: "memory"); }
            else { asm volatile("s_waitcnt vmcnt(10)" ::: "memory"); }
        } else {
            if (GL == 0) { asm volatile("s_waitcnt vmcnt(16)" ::: "memory"); }
            else { asm volatile("s_waitcnt vmcnt(2)" ::: "memory"); }
        }
        blockbar();
        const char* Wb = (const char*)&wqs[buf][0][0];
        float4v acc[2][2] = {};
#pragma unroll
        for (int kd = 0; kd < 16; kd++) {
            short8 b0 = *(const short8*)(Wb + lr * 1024 + ((kd * 64) ^ hq));
            short8 b1 = *(const short8*)(Wb + (16 + lr) * 1024 + ((kd * 64) ^ hq));
            acc[0][0] = __builtin_amdgcn_mfma_f32_16x16x32_bf16(a[0][kd], b0, acc[0][0], 0, 0, 0);
            acc[0][1] = __builtin_amdgcn_mfma_f32_16x16x32_bf16(a[0][kd], b1, acc[0][1], 0, 0, 0);
            acc[1][0] = __builtin_amdgcn_mfma_f32_16x16x32_bf16(a[1][kd], b0, acc[1][0], 0, 0, 0);
            acc[1][1] = __builtin_amdgcn_mfma_f32_16x16x32_bf16(a[1][kd], b1, acc[1][1], 0, 0, 0);
        }
        if (GL == 0) {
#pragma unroll
            for (int i = 0; i < 2; i++)
#pragma unroll
                for (int j = 0; j < 2; j++) {
                    int col = t * 32 + j * 16 + lr;
                    float bv = bias[col];
#pragma unroll
                    for (int r = 0; r < 4; r++) {
                        int row = i * 16 + lk * 4 + r;
                        Dlin[(size_t)row * DI_ + col] = f2bf(acc[i][j][r] + bv);
                    }
                }
        } else {
#pragma unroll
            for (int i = 0; i < 2; i++) {
                int sm = (i * 2 + (lk >> 1)) & 3;
#pragma unroll
                for (int j = 0; j < 2; j++) {
                    int dd = j * 16 + lr;
                    int slot = dd * 4 + (sm ^ ((dd >> 3) & 3));
                    float bv = bias[t * 32 + dd];
                    short4v pk;
#pragma unroll
                    for (int r = 0; r < 4; r++) pk[r] = (short)f2bf(acc[i][j][r] + bv);
                    *(short4v*)(&gscr[wave * 1024 + slot * 8 + (lk & 1) * 4]) = pk;
                }
            }
            asm volatile("s_waitcnt lgkmcnt(0)" ::: "memory");
            blockbar();
#pragma unroll
            for (int r2 = 0; r2 < 2; r2++) {
                int idx = r2 * 256 + threadIdx.x;
                int w = idx >> 7;
                int o2 = (idx * 8) & 1023;
                short8 v = *(const short8*)(&gscr[idx * 8]);
                *(short8*)(Dg + (size_t)(nblk * 4 + w) * 8192 + t * 1024 + o2) = v;
            }
        }
        blockbar();
        buf ^= 1;
    }
}

// ---------- out GEMM, LDS-staged, int16 fixed-point output + fused BN partial sums ----------
__global__ __launch_bounds__(256, 2) void out_gemm(
        const unsigned short* __restrict__ wo,
        const unsigned short* __restrict__ Bh, const unsigned short* __restrict__ Bl,
        unsigned short* __restrict__ Dp, const float* __restrict__ bias,
        float* __restrict__ psum) {
    __shared__ __align__(16) unsigned short tts[2][2][32][256];  // 64KB
    const int bid = blockIdx.x;
    const int b = bid & 7;
    const int rem = bid >> 3;
    const int doblk = rem & 3;
    const int nchunk = rem >> 2;
    const int wave = threadIdx.x >> 6, lane = threadIdx.x & 63;
    const int lr = lane & 15, lk = lane >> 4;
    const unsigned short* Ab = wo + (size_t)(doblk * 128 + wave * 32) * DI_;
    const unsigned short* BhB = Bh + ((size_t)b * N_ + nchunk * 128) * DI_;
    const unsigned short* BlB = Bl + ((size_t)b * N_ + nchunk * 128) * DI_;

    short8 a[2][8];
#pragma unroll
    for (int i = 0; i < 2; i++)
#pragma unroll
        for (int kd = 0; kd < 8; kd++)
            a[i][kd] = *(const short8*)(Ab + (size_t)(i * 16 + lr) * DI_ + kd * 32 + lk * 8);

    auto stage = [&](int bufi, int t) {
#pragma unroll
        for (int p = 0; p < 2; p++) {
            const unsigned short* S = p ? BlB : BhB;
#pragma unroll
            for (int j = 0; j < 4; j++) {
                int chunk = wave * 4 + j;
                int row = chunk * 2 + (lane >> 5);
                int qq = (((lane & 31) * 16)) ^ ((row & 7) << 4);
                const unsigned short* src = S + (size_t)(t * 32 + row) * DI_ + (qq >> 1);
                unsigned short* dst = &tts[bufi][p][0][0] + chunk * 512;
                __builtin_amdgcn_global_load_lds(
                    (const __attribute__((address_space(1))) unsigned int*)src,
                    (__attribute__((address_space(3))) unsigned int*)dst, 16, 0, 0);
            }
        }
    };

    stage(0, 0);
    const int hq = (lk * 16) ^ ((lr & 7) << 4);
    float4v acc[4][2][2] = {};
    int buf = 0;
#pragma unroll
    for (int t = 0; t < 4; t++) {
        if (t < 3) {
            stage(buf ^ 1, t + 1);
            asm volatile("s_waitcnt vmcnt(8)" ::: "memory");
        } else {
            asm volatile("s_waitcnt vmcnt(0)" ::: "memory");
        }
        blockbar();
        const char* th = (const char*)&tts[buf][0][0][0];
        const char* tl = (const char*)&tts[buf][1][0][0];
#pragma unroll
        for (int kd = 0; kd < 8; kd++) {
            short8 bh0 = *(const short8*)(th + lr * 512 + ((kd * 64) ^ hq));
            short8 bh1 = *(const short8*)(th + (16 + lr) * 512 + ((kd * 64) ^ hq));
            short8 bl0 = *(const short8*)(tl + lr * 512 + ((kd * 64) ^ hq));
            short8 bl1 = *(const short8*)(tl + (16 + lr) * 512 + ((kd * 64) ^ hq));
            acc[t][0][0] = __builtin_amdgcn_mfma_f32_16x16x32_bf16(a[0][kd], bh0, acc[t][0][0], 0, 0, 0);
            acc[t][0][0] = __builtin_amdgcn_mfma_f32_16x16x32_bf16(a[0][kd], bl0, acc[t][0][0], 0, 0, 0);
            acc[t][0][1] = __builtin_amdgcn_mfma_f32_16x16x32_bf16(a[0][kd], bh1, acc[t][0][1], 0, 0, 0);
            acc[t][0][1] = __builtin_amdgcn_mfma_f32_16x16x32_bf16(a[0][kd], bl1, acc[t][0][1], 0, 0, 0);
            acc[t][1][0] = __builtin_amdgcn_mfma_f32_16x16x32_bf16(a[1][kd], bh0, acc[t][1][0], 0, 0, 0);
            acc[t][1][0] = __builtin_amdgcn_mfma_f32_16x16x32_bf16(a[1][kd], bl0, acc[t][1][0], 0, 0, 0);
            acc[t][1][1] = __builtin_amdgcn_mfma_f32_16x16x32_bf16(a[1][kd], bh1, acc[t][1][1], 0, 0, 0);
            acc[t][1][1] = __builtin_amdgcn_mfma_f32_16x16x32_bf16(a[1][kd], bl1, acc[t][1][1], 0, 0, 0);
        }
        blockbar();
        buf ^= 1;
    }
    unsigned short* Db = Dp + (size_t)b * DO_ * N_;
    float s1[2][4] = {}, s2[2][4] = {};
#pragma unroll
    for (int t = 0; t < 4; t++)
#pragma unroll
        for (int i = 0; i < 2; i++)
#pragma unroll
            for (int r = 0; r < 4; r++) {
                int dorow = doblk * 128 + wave * 32 + i * 16 + lk * 4 + r;
                float bv = bias[dorow];
                float v0 = acc[t][i][0][r] + bv;
                float v1 = acc[t][i][1][r] + bv;
                int ncol = nchunk * 128 + t * 32 + lr;
                float c0 = fminf(fmaxf(v0 * Q_SCALE, -32767.f), 32767.f);
                float c1 = fminf(fmaxf(v1 * Q_SCALE, -32767.f), 32767.f);
                Db[(size_t)dorow * N_ + ncol] = (unsigned short)(short)lrintf(c0);
                Db[(size_t)dorow * N_ + ncol + 16] = (unsigned short)(short)lrintf(c1);
                s1[i][r] += v0 + v1;
                s2[i][r] += v0 * v0 + v1 * v1;
            }
#pragma unroll
    for (int m = 1; m < 16; m <<= 1)
#pragma unroll
        for (int i = 0; i < 2; i++)
#pragma unroll
            for (int r = 0; r < 4; r++) {
                s1[i][r] += __shfl_xor(s1[i][r], m, 64);
                s2[i][r] += __shfl_xor(s2[i][r], m, 64);
            }
    if (lr == 0) {
        int pcol = b * 49 + nchunk;
#pragma unroll
        for (int i = 0; i < 2; i++)
#pragma unroll
            for (int r = 0; r < 4; r++) {
                int row = doblk * 128 + wave * 32 + i * 16 + lk * 4 + r;
                psum[(size_t)row * PSUM_COLS + pcol] = s1[i][r];
                psum[(size_t)(DO_ + row) * PSUM_COLS + pcol] = s2[i][r];
            }
    }
}

// ---------- fused attention (round-10 structure: 4 waves, 32 q-rows/wave) ----------
__global__ __launch_bounds__(256, 2) void attn_k(
        const unsigned short* __restrict__ thetaT,
        const unsigned short* __restrict__ phiT,
        const unsigned short* __restrict__ g,
        unsigned short* __restrict__ ttH,
        unsigned short* __restrict__ ttL) {
    __shared__ __align__(16) unsigned short phi_s[2][32][256];  // 32KB
    __shared__ __align__(16) unsigned short g_s[2][8192];       // 32KB
    const int bid = blockIdx.x;
    const int b = bid & 7;
    const int nblk = bid >> 3;
    const int wave = threadIdx.x >> 6, lane = threadIdx.x & 63;
    const int l31 = lane & 31, hi = lane >> 5;
    const int n0 = nblk * 128 + wave * 32;
    const unsigned short* Q  = thetaT + ((size_t)b * N_ + n0) * DI_;
    const unsigned short* Pg = phiT + (size_t)b * PG_BS;
    const unsigned short* G  = g + (size_t)b * PG_BS;

    short8 q[16];
#pragma unroll
    for (int kb = 0; kb < 16; kb++)
        q[kb] = *(const short8*)(Q + (size_t)l31 * DI_ + kb * 16 + hi * 8);

    float16v acc[8] = {};
    float rs = 0.f;

    auto stage = [&](int bufi, int t) {
        const unsigned short* phiRow = Pg + (size_t)t * 32 * DI_;
#pragma unroll
        for (int j = 0; j < 4; j++) {
            int chunk = wave * 4 + j;
            int row = chunk * 2 + (lane >> 5);
            int qq = ((lane & 31) * 16) ^ ((row & 31) << 4);
            const unsigned short* src = phiRow + (size_t)row * DI_ + (qq >> 1);
            unsigned short* dst = &phi_s[bufi][0][0] + chunk * 512;
            __builtin_amdgcn_global_load_lds(
                (const __attribute__((address_space(1))) unsigned int*)src,
                (__attribute__((address_space(3))) unsigned int*)dst, 16, 0, 0);
        }
        const unsigned short* Gt = G + (size_t)t * 8192;
#pragma unroll
        for (int j = 0; j < 4; j++) {
            int chunk = wave * 4 + j;
            const unsigned short* src = Gt + chunk * 512 + lane * 8;
            unsigned short* dst = &g_s[bufi][0] + chunk * 512;
            __builtin_amdgcn_global_load_lds(
                (const __attribute__((address_space(1))) unsigned int*)src,
                (__attribute__((address_space(3))) unsigned int*)dst, 16, 0, 0);
        }
    };

    stage(0, 0);
    const int pswz = l31 << 4;
    const int glow = hi ^ ((l31 >> 3) & 3);
    const int goff0 = (l31 * 4 + glow) << 4;
    const int goff1 = goff0 ^ 32;
    int buf = 0;
    const int NT = M_ / 32;  // 49
    for (int t = 0; t < NT; t++) {
        if (t + 1 < NT) {
            stage(buf ^ 1, t + 1);
            asm volatile("s_waitcnt vmcnt(8)" ::: "memory");
        } else {
            asm volatile("s_waitcnt vmcnt(0)" ::: "memory");
        }
        blockbar();

        const char* phiB = (const char*)&phi_s[buf][0][0];
        float16v S0 = {}, S1 = {};
        __builtin_amdgcn_s_setprio(1);
#pragma unroll
        for (int kb = 0; kb < 8; kb++) {
            short8 pha0 = *(const short8*)(phiB + l31 * 512 + ((kb * 32 + hi * 16) ^ pswz));
            short8 pha1 = *(const short8*)(phiB + l31 * 512 + (((kb + 8) * 32 + hi * 16) ^ pswz));
            S0 = __builtin_amdgcn_mfma_f32_32x32x16_bf16(pha0, q[kb], S0, 0, 0, 0);
            S1 = __builtin_amdgcn_mfma_f32_32x32x16_bf16(pha1, q[kb + 8], S1, 0, 0, 0);
        }
        __builtin_amdgcn_s_setprio(0);

        float p[16];
#pragma unroll
        for (int r = 0; r < 16; r++) {
            p[r] = exp2f((S0[r] + S1[r]) * SCALE_LOG2E);
            rs += p[r];
        }
        unsigned int pk0, pk1, pk2, pk3, pk4, pk5, pk6, pk7;
        asm("v_cvt_pk_bf16_f32 %0, %1, %2" : "=v"(pk0) : "v"(p[0]),  "v"(p[1]));
        asm("v_cvt_pk_bf16_f32 %0, %1, %2" : "=v"(pk1) : "v"(p[2]),  "v"(p[3]));
        asm("v_cvt_pk_bf16_f32 %0, %1, %2" : "=v"(pk2) : "v"(p[4]),  "v"(p[5]));
        asm("v_cvt_pk_bf16_f32 %0, %1, %2" : "=v"(pk3) : "v"(p[6]),  "v"(p[7]));
        asm("v_cvt_pk_bf16_f32 %0, %1, %2" : "=v"(pk4) : "v"(p[8]),  "v"(p[9]));
        asm("v_cvt_pk_bf16_f32 %0, %1, %2" : "=v"(pk5) : "v"(p[10]), "v"(p[11]));
        asm("v_cvt_pk_bf16_f32 %0, %1, %2" : "=v"(pk6) : "v"(p[12]), "v"(p[13]));
        asm("v_cvt_pk_bf16_f32 %0, %1, %2" : "=v"(pk7) : "v"(p[14]), "v"(p[15]));
        asm("v_permlane32_swap_b32 %0, %1" : "+v"(pk0), "+v"(pk2));
        asm("v_permlane32_swap_b32 %0, %1" : "+v"(pk1), "+v"(pk3));
        asm("v_permlane32_swap_b32 %0, %1" : "+v"(pk4), "+v"(pk6));
        asm("v_permlane32_swap_b32 %0, %1" : "+v"(pk5), "+v"(pk7));
        union UF { unsigned int u[4]; short8 s; } pa0, pa1;
        pa0.u[0] = pk0; pa0.u[1] = pk1; pa0.u[2] = pk2; pa0.u[3] = pk3;
        pa1.u[0] = pk4; pa1.u[1] = pk5; pa1.u[2] = pk6; pa1.u[3] = pk7;

        const char* gB = (const char*)&g_s[buf][0];
        __builtin_amdgcn_s_setprio(1);
#pragma unroll
        for (int dblk = 0; dblk < 8; dblk++) {
            short8 gb0 = *(const short8*)(gB + dblk * 2048 + goff0);
            short8 gb1 = *(const short8*)(gB + dblk * 2048 + goff1);
            acc[dblk] = __builtin_amdgcn_mfma_f32_32x32x16_bf16(pa0.s, gb0, acc[dblk], 0, 0, 0);
            acc[dblk] = __builtin_amdgcn_mfma_f32_32x32x16_bf16(pa1.s, gb1, acc[dblk], 0, 0, 0);
        }
        __builtin_amdgcn_s_setprio(0);
        blockbar();
        buf ^= 1;
    }

    rs += __shfl_xor(rs, 32, 64);
    float inv = 1.0f / rs;

    unsigned short* OH = ttH + ((size_t)b * N_ + n0) * DI_;
    unsigned short* OL = ttL + ((size_t)b * N_ + n0) * DI_;
#pragma unroll
    for (int reg = 0; reg < 16; reg++) {
        int n_l = (reg & 3) + 8 * (reg >> 2) + 4 * hi;
        float invn = __shfl(inv, n_l, 64);
#pragma unroll
        for (int dblk = 0; dblk < 8; dblk++) {
            float v = acc[dblk][reg] * invn;
            unsigned short h = f2bf(v);
            unsigned short l = f2bf(v - bf2f(h));
            size_t idx = (size_t)n_l * DI_ + dblk * 32 + l31;
            OH[idx] = h;
            OL[idx] = l;
        }
    }
}

// ---------- BN finalize ----------
__global__ void bn_finalize(const float* __restrict__ psum, float* __restrict__ stats) {
    int o = blockIdx.x;
    float s = 0.f, q = 0.f;
    for (int c = threadIdx.x; c < PSUM_COLS; c += 256) {
        s += psum[(size_t)o * PSUM_COLS + c];
        q += psum[(size_t)(DO_ + o) * PSUM_COLS + c];
    }
#pragma unroll
    for (int m = 1; m < 64; m <<= 1) { s += __shfl_xor(s, m, 64); q += __shfl_xor(q, m, 64); }
    __shared__ float ws1[4], ws2[4];
    int wave = threadIdx.x >> 6;
    if ((threadIdx.x & 63) == 0) { ws1[wave] = s; ws2[wave] = q; }
    __syncthreads();
    if (threadIdx.x == 0) {
        double S = (double)ws1[0] + ws1[1] + ws1[2] + ws1[3];
        double Q = (double)ws2[0] + ws2[1] + ws2[2] + ws2[3];
        const double cnt = (double)(B_ * N_);
        double mean = S / cnt;
        double var = Q / cnt - mean * mean;
        stats[o] = (float)mean;
        stats[DO_ + o] = (float)(1.0 / sqrt(var + (double)BN_EPS));
    }
}

// ---------- BN apply + residual: reads int16 fixed-point pre-BN out ----------
__global__ void bn_apply(const unsigned short* __restrict__ ob, const float* __restrict__ x,
                         const float* __restrict__ stats, const float* __restrict__ gamma,
                         const float* __restrict__ beta, float* __restrict__ out) {
    size_t i = ((size_t)blockIdx.x * 256 + threadIdx.x) * 8;
    short8 v8 = *(const short8*)(ob + i);
    int o = (int)((i / N_) % DO_);
    float mean = stats[o], rsig = stats[DO_ + o];
    float ga = gamma[o], be = beta[o];
    float4v x0 = *(const float4v*)(x + i);
    float4v x1 = *(const float4v*)(x + i + 4);
    float4v r0, r1;
#pragma unroll
    for (int j = 0; j < 4; j++) {
        r0[j] = ((float)(short)v8[j] * Q_INV - mean) * rsig * ga + be + x0[j];
        r1[j] = ((float)(short)v8[4 + j] * Q_INV - mean) * rsig * ga + be + x1[j];
    }
    *(float4v*)(out + i) = r0;
    *(float4v*)(out + i + 4) = r1;
}

extern "C" void kernel_launch(void* const* d_in, const int* in_sizes, int n_in,
                              void* d_out, int out_size, void* d_ws, size_t ws_size,
                              hipStream_t stream) {
    const float* x       = (const float*)d_in[0];
    const float* theta_w = (const float*)d_in[1];
    const float* theta_b = (const float*)d_in[2];
    const float* phi_w   = (const float*)d_in[3];
    const float* phi_b   = (const float*)d_in[4];
    const float* g_w     = (const float*)d_in[5];
    const float* g_b     = (const float*)d_in[6];
    const float* out_w   = (const float*)d_in[7];
    const float* out_b   = (const float*)d_in[8];
    const float* bn_g    = (const float*)d_in[9];
    const float* bn_b    = (const float*)d_in[10];
    float* out = (float*)d_out;

    char* ws = (char*)d_ws;
    size_t off = 0;
    auto alloc = [&](size_t bytes) { void* p = ws + off; off += (bytes + 255) & ~(size_t)255; return p; };
    unsigned short* xT     = (unsigned short*)alloc((size_t)B_ * N_ * C_ * 2);
    unsigned short* mpT    = (unsigned short*)alloc((size_t)B_ * M_ * C_ * 2);
    unsigned short* thetaT = (unsigned short*)alloc((size_t)B_ * N_ * DI_ * 2);
    unsigned short* phiT   = (unsigned short*)alloc((size_t)B_ * PG_BS * 2);   // padded
    unsigned short* gbuf   = (unsigned short*)alloc((size_t)B_ * PG_BS * 2);   // padded
    unsigned short* wq     = (unsigned short*)alloc((size_t)DI_ * C_ * 2);
    unsigned short* wp     = (unsigned short*)alloc((size_t)DI_ * C_ * 2);
    unsigned short* wg     = (unsigned short*)alloc((size_t)DI_ * C_ * 2);
    unsigned short* wo     = (unsigned short*)alloc((size_t)DO_ * DI_ * 2);
    float* stats           = (float*)alloc((size_t)DO_ * 2 * 4);
    float* psum            = (float*)alloc((size_t)DO_ * 2 * PSUM_COLS * 4);
    unsigned short* ttH    = xT;                               // xT dead after theta
    unsigned short* ttL    = xT + (size_t)B_ * N_ * DI_;
    unsigned short* out_q  = mpT;  // mpT..gbuf region dead after attn

    cast_w4<<<dim3(512, 4), 256, 0, stream>>>(theta_w, phi_w, g_w, out_w, wq, wp, wg, wo);

    xpose_x<<<dim3(N_ / 64, C_ / 64, B_), 256, 0, stream>>>(x, xT);
    pool_from_xT<<<dim3(M_ / 2, B_), 256, 0, stream>>>(xT, mpT);

    proj_gemm<0><<<392, 256, 0, stream>>>(xT, N_, wq, thetaT, (size_t)N_ * DI_, theta_b);
    proj_gemm<0><<<104, 256, 0, stream>>>(mpT, M_, wp, phiT, (size_t)PG_BS, phi_b);
    proj_gemm<1><<<104, 256, 0, stream>>>(mpT, M_, wg, gbuf, (size_t)PG_BS, g_b);

    attn_k<<<dim3((N_ / 128) * 8), 256, 0, stream>>>(thetaT, phiT, gbuf, ttH, ttL);

    out_gemm<<<1568, 256, 0, stream>>>(wo, ttH, ttL, out_q, out_b, psum);

    bn_finalize<<<DO_, 256, 0, stream>>>(psum, stats);
    bn_apply<<<(size_t)B_ * DO_ * N_ / 8 / 256, 256, 0, stream>>>(out_q, x, stats, bn_g, bn_b, out);
}